// Round 2
// baseline (7628.310 us; speedup 1.0000x reference)
//
#include <hip/hip_runtime.h>

#define NN 50000
#define FF 24
#define HH 128
#define TT 12
#define EE 800000
#define HORZ 6

// ---------------- mask dtype detection + canonicalization ----------------
// mask_seq is a jax bool array; the harness may push it as 1-byte bool or
// widened int32. Detect on-device: in int32 layout (values 0/1), every byte
// at offset i%4!=0 is zero; in byte layout ~90% of all bytes are 1.

__global__ void k_maskdetect(const unsigned char* __restrict__ m, int* __restrict__ flag) {
    int i = blockIdx.x * 256 + threadIdx.x;
    if (i < 16384 && (i & 3) != 0 && m[i] != 0) atomicOr(flag, 1);
}

__global__ void k_maskconv(const unsigned char* __restrict__ mraw, const int* __restrict__ flag,
                           unsigned char* __restrict__ mout) {
    int i = blockIdx.x * 256 + threadIdx.x;
    if (i >= TT * NN) return;
    if (*flag) mout[i] = (mraw[i] != 0);                       // byte/bool layout
    else       mout[i] = (((const int*)mraw)[i] != 0);         // int32 layout
}

// ---------------- degree / norm precompute ----------------

__global__ void k_deg(const int* __restrict__ ei, const float* __restrict__ ea,
                      float* __restrict__ deg) {
    int idx = blockIdx.x * 256 + threadIdx.x;          // over T*E
    if (idx >= TT * EE) return;
    int t = idx / EE, e = idx - t * EE;
    int dst = ei[((size_t)t * 2 + 1) * EE + e];
    atomicAdd(&deg[t * NN + dst], ea[idx]);
}

__global__ void k_dinv(float* __restrict__ deg) {
    int idx = blockIdx.x * 256 + threadIdx.x;          // over T*N
    if (idx >= TT * NN) return;
    deg[idx] = rsqrtf(deg[idx] + 1.0f);                // dinv = 1/sqrt(deg+1); 1/deg_tot = dinv^2
}

// ---------------- h_prev build (mask gate) ----------------
// h_store[n] == 0 until first masked update, so (mask & seen) ? h_store : 0 == mask ? h_store : 0

__global__ void k_hp(const float* __restrict__ hstore, const unsigned char* __restrict__ mask,
                     float* __restrict__ hp) {
    int idx = blockIdx.x * 256 + threadIdx.x;          // over N*H
    if (idx >= NN * HH) return;
    int n = idx >> 7;
    hp[idx] = mask[n] ? hstore[idx] : 0.0f;
}

// ---------------- edge scatter in feature space (F=24) ----------------

__global__ void k_scatter(const float* __restrict__ x, const int* __restrict__ src,
                          const int* __restrict__ dst, const float* __restrict__ ea,
                          const float* __restrict__ dinv, float* __restrict__ aggx) {
    int idx = blockIdx.x * 256 + threadIdx.x;          // over E*F
    if (idx >= EE * FF) return;
    int e = idx / FF, f = idx - e * FF;
    int s = src[e], d = dst[e];
    float c = dinv[s] * ea[e] * dinv[d];
    atomicAdd(&aggx[d * FF + f], x[s * FF + f] * c);
}

// ---------------- G = (aggx + x*invdeg) @ [Wz|Wr|Wh] + [bz|br|bh]  (K=24) ----------------

__global__ void k_ggemm(const float* __restrict__ x, const float* __restrict__ aggx,
                        const float* __restrict__ dinv,
                        const float* __restrict__ Wz, const float* __restrict__ Wr,
                        const float* __restrict__ Wh,
                        const float* __restrict__ bz, const float* __restrict__ br,
                        const float* __restrict__ bh,
                        float* __restrict__ G) {
    __shared__ float xe[8][FF];
    int nb = blockIdx.x * 8;
    int tid = threadIdx.x;                              // 384 threads
    if (tid < 8 * FF) {
        int m = tid / FF, f = tid - m * FF;
        int n = nb + m;
        float id = dinv[n];
        xe[m][f] = aggx[n * FF + f] + x[n * FF + f] * (id * id);
    }
    __syncthreads();
    int g = tid >> 7, c = tid & 127;
    const float* W = (g == 0) ? Wz : ((g == 1) ? Wr : Wh);
    const float* B = (g == 0) ? bz : ((g == 1) ? br : bh);
    float acc[8];
    float b = B[c];
#pragma unroll
    for (int m = 0; m < 8; m++) acc[m] = b;
#pragma unroll
    for (int k = 0; k < FF; k++) {
        float w = W[k * HH + c];
#pragma unroll
        for (int m = 0; m < 8; m++) acc[m] += xe[m][k] * w;
    }
#pragma unroll
    for (int m = 0; m < 8; m++) G[(size_t)(nb + m) * 384 + g * 128 + c] = acc[m];
}

// ---------------- z,r gates: sigmoid(Gpart @ LW_top + hp @ LW_bot + Lb) ----------------

__global__ void k_zr(const float* __restrict__ G, const float* __restrict__ hp,
                     const float* __restrict__ LWz, const float* __restrict__ LWr,
                     const float* __restrict__ Lbz, const float* __restrict__ Lbr,
                     float* __restrict__ zb, float* __restrict__ rb) {
    __shared__ float Az[8][HH], Ar[8][HH], Ah[8][HH];
    int nb = blockIdx.x * 8;
    int tid = threadIdx.x;                              // 256 threads
    for (int i = tid; i < 8 * HH; i += 256) {
        int m = i >> 7, k = i & 127;
        int n = nb + m;
        Az[m][k] = G[(size_t)n * 384 + k];
        Ar[m][k] = G[(size_t)n * 384 + 128 + k];
        Ah[m][k] = hp[n * HH + k];
    }
    __syncthreads();
    int g = tid >> 7, c = tid & 127;
    const float* LW = g ? LWr : LWz;
    float acc[8];
    float b = (g ? Lbr : Lbz)[c];
#pragma unroll
    for (int m = 0; m < 8; m++) acc[m] = b;
    const float (*A)[HH] = g ? Ar : Az;
    for (int k = 0; k < HH; k += 4) {
        float w0 = LW[(k + 0) * HH + c];
        float w1 = LW[(k + 1) * HH + c];
        float w2 = LW[(k + 2) * HH + c];
        float w3 = LW[(k + 3) * HH + c];
#pragma unroll
        for (int m = 0; m < 8; m++) {
            const float4 a = *reinterpret_cast<const float4*>(&A[m][k]);
            acc[m] += a.x * w0 + a.y * w1 + a.z * w2 + a.w * w3;
        }
    }
    for (int k = 0; k < HH; k += 4) {
        float w0 = LW[(HH + k + 0) * HH + c];
        float w1 = LW[(HH + k + 1) * HH + c];
        float w2 = LW[(HH + k + 2) * HH + c];
        float w3 = LW[(HH + k + 3) * HH + c];
#pragma unroll
        for (int m = 0; m < 8; m++) {
            const float4 a = *reinterpret_cast<const float4*>(&Ah[m][k]);
            acc[m] += a.x * w0 + a.y * w1 + a.z * w2 + a.w * w3;
        }
    }
    float* outp = g ? rb : zb;
#pragma unroll
    for (int m = 0; m < 8; m++) {
        outp[(nb + m) * HH + c] = 1.0f / (1.0f + __expf(-acc[m]));
    }
}

// ---------------- htil + GRU update (+ masked h_store write) ----------------

__global__ void k_htil(const float* __restrict__ G, const float* __restrict__ hp,
                       const float* __restrict__ rb, const float* __restrict__ zb,
                       const float* __restrict__ LWh, const float* __restrict__ Lbh,
                       const unsigned char* __restrict__ mask,
                       float* __restrict__ hout) {
    __shared__ float Ag[8][HH], Hr[8][HH];
    int nb = blockIdx.x * 8;
    int tid = threadIdx.x;                              // 128 threads
    for (int i = tid; i < 8 * HH; i += 128) {
        int m = i >> 7, k = i & 127;
        int n = nb + m;
        Ag[m][k] = G[(size_t)n * 384 + 256 + k];
        Hr[m][k] = hp[n * HH + k] * rb[n * HH + k];
    }
    __syncthreads();
    int c = tid;
    float acc[8];
    float b = Lbh[c];
#pragma unroll
    for (int m = 0; m < 8; m++) acc[m] = b;
    for (int k = 0; k < HH; k += 4) {
        float w0 = LWh[(k + 0) * HH + c];
        float w1 = LWh[(k + 1) * HH + c];
        float w2 = LWh[(k + 2) * HH + c];
        float w3 = LWh[(k + 3) * HH + c];
#pragma unroll
        for (int m = 0; m < 8; m++) {
            const float4 a = *reinterpret_cast<const float4*>(&Ag[m][k]);
            acc[m] += a.x * w0 + a.y * w1 + a.z * w2 + a.w * w3;
        }
    }
    for (int k = 0; k < HH; k += 4) {
        float w0 = LWh[(HH + k + 0) * HH + c];
        float w1 = LWh[(HH + k + 1) * HH + c];
        float w2 = LWh[(HH + k + 2) * HH + c];
        float w3 = LWh[(HH + k + 3) * HH + c];
#pragma unroll
        for (int m = 0; m < 8; m++) {
            const float4 a = *reinterpret_cast<const float4*>(&Hr[m][k]);
            acc[m] += a.x * w0 + a.y * w1 + a.z * w2 + a.w * w3;
        }
    }
#pragma unroll
    for (int m = 0; m < 8; m++) {
        int n = nb + m;
        float ht = tanhf(acc[m]);
        float z = zb[n * HH + c];
        float h0 = hp[n * HH + c];
        float hn = z * h0 + (1.0f - z) * ht;
        if (mask) {
            if (mask[n]) hout[n * HH + c] = hn;
        } else {
            hout[n * HH + c] = hn;
        }
    }
}

// ---------------- decoder head: y = h @ headW + headb ----------------

__global__ void k_head(const float* __restrict__ h, const float* __restrict__ headW,
                       const float* __restrict__ headb, float* __restrict__ y) {
    int idx = blockIdx.x * 256 + threadIdx.x;           // over N*F
    if (idx >= NN * FF) return;
    int n = idx / FF, f = idx - n * FF;
    float acc = headb[f];
#pragma unroll 4
    for (int c = 0; c < HH; c++) acc += h[n * HH + c] * headW[c * FF + f];
    y[idx] = acc;
}

extern "C" void kernel_launch(void* const* d_in, const int* in_sizes, int n_in,
                              void* d_out, int out_size, void* d_ws, size_t ws_size,
                              hipStream_t stream) {
    const float* x_seq = (const float*)d_in[0];
    const int*   ei    = (const int*)d_in[1];
    const float* ea    = (const float*)d_in[2];
    const unsigned char* mraw = (const unsigned char*)d_in[3];
    // d_in[4] = id_seq (unused)
    const float* Wz  = (const float*)d_in[5];
    const float* Wr  = (const float*)d_in[6];
    const float* Wh  = (const float*)d_in[7];
    const float* bz  = (const float*)d_in[8];
    const float* br  = (const float*)d_in[9];
    const float* bh  = (const float*)d_in[10];
    const float* LWz = (const float*)d_in[11];
    const float* LWr = (const float*)d_in[12];
    const float* LWh = (const float*)d_in[13];
    const float* Lbz = (const float*)d_in[14];
    const float* Lbr = (const float*)d_in[15];
    const float* Lbh = (const float*)d_in[16];
    const float* headW = (const float*)d_in[17];
    const float* headb = (const float*)d_in[18];
    float* out = (float*)d_out;

    float* wp = (float*)d_ws;
    float* dinv   = wp; wp += (size_t)TT * NN;
    float* hstore = wp; wp += (size_t)NN * HH;
    float* hp     = wp; wp += (size_t)NN * HH;
    float* aggx   = wp; wp += (size_t)NN * FF;
    float* G      = wp; wp += (size_t)NN * 384;
    float* zb     = wp; wp += (size_t)NN * HH;
    float* rb     = wp; wp += (size_t)NN * HH;
    int*   mflag  = (int*)wp; wp += 64;                       // detection flag
    unsigned char* mask = (unsigned char*)wp;                 // T*N canonical mask
    wp += (TT * NN + 255) / 256 * 64;
    size_t need_bytes = (size_t)(wp - (float*)d_ws) * sizeof(float);
    if (ws_size < need_bytes) return;   // diagnosable: leaves d_out at memset value

    hipMemsetAsync(mflag, 0, sizeof(int), stream);
    k_maskdetect<<<64, 256, 0, stream>>>(mraw, mflag);
    k_maskconv<<<(TT * NN + 255) / 256, 256, 0, stream>>>(mraw, mflag, mask);

    hipMemsetAsync(dinv, 0, sizeof(float) * TT * NN, stream);
    hipMemsetAsync(hstore, 0, sizeof(float) * NN * HH, stream);
    k_deg<<<(TT * EE + 255) / 256, 256, 0, stream>>>(ei, ea, dinv);
    k_dinv<<<(TT * NN + 255) / 256, 256, 0, stream>>>(dinv);

    // ---------------- encoder ----------------
    for (int t = 0; t < TT; t++) {
        const float* xt  = x_seq + (size_t)t * NN * FF;
        const int*   src = ei + (size_t)t * 2 * EE;
        const int*   dst = src + EE;
        const float* eat = ea + (size_t)t * EE;
        const float* dit = dinv + (size_t)t * NN;
        const unsigned char* mt = mask + (size_t)t * NN;

        k_hp<<<(NN * HH + 255) / 256, 256, 0, stream>>>(hstore, mt, hp);
        hipMemsetAsync(aggx, 0, sizeof(float) * NN * FF, stream);
        k_scatter<<<(EE * FF + 255) / 256, 256, 0, stream>>>(xt, src, dst, eat, dit, aggx);
        k_ggemm<<<NN / 8, 384, 0, stream>>>(xt, aggx, dit, Wz, Wr, Wh, bz, br, bh, G);
        k_zr<<<NN / 8, 256, 0, stream>>>(G, hp, LWz, LWr, Lbz, Lbr, zb, rb);
        k_htil<<<NN / 8, 128, 0, stream>>>(G, hp, rb, zb, LWh, Lbh, mt, hstore);
    }

    // ---------------- decoder ----------------
    k_hp<<<(NN * HH + 255) / 256, 256, 0, stream>>>(hstore, mask + (size_t)(TT - 1) * NN, hp);
    const int*   srcl = ei + (size_t)(TT - 1) * 2 * EE;
    const int*   dstl = srcl + EE;
    const float* eal  = ea + (size_t)(TT - 1) * EE;
    const float* dil  = dinv + (size_t)(TT - 1) * NN;
    for (int k = 0; k < HORZ; k++) {
        const float* xin = (k == 0) ? (x_seq + (size_t)(TT - 1) * NN * FF)
                                    : (out + (size_t)(k - 1) * NN * FF);
        hipMemsetAsync(aggx, 0, sizeof(float) * NN * FF, stream);
        k_scatter<<<(EE * FF + 255) / 256, 256, 0, stream>>>(xin, srcl, dstl, eal, dil, aggx);
        k_ggemm<<<NN / 8, 384, 0, stream>>>(xin, aggx, dil, Wz, Wr, Wh, bz, br, bh, G);
        k_zr<<<NN / 8, 256, 0, stream>>>(G, hp, LWz, LWr, Lbz, Lbr, zb, rb);
        k_htil<<<NN / 8, 128, 0, stream>>>(G, hp, rb, zb, LWh, Lbh, nullptr, hp);
        k_head<<<(NN * FF + 255) / 256, 256, 0, stream>>>(hp, headW, headb, out + (size_t)k * NN * FF);
    }
}